// Round 7
// baseline (547.384 us; speedup 1.0000x reference)
//
#include <hip/hip_runtime.h>
#include <hip/hip_bf16.h>

typedef __attribute__((ext_vector_type(8))) short short8;
typedef __attribute__((ext_vector_type(4))) float floatx4;

#define B_    4
#define S_    2048
#define EMB_  1024
#define NH_   16
#define HD_   64

#define EXP2F(x) exp2f(x)

__device__ __forceinline__ void async_cp16(const void* g, void* l) {
  __builtin_amdgcn_global_load_lds(
      (const __attribute__((address_space(1))) unsigned int*)g,
      (__attribute__((address_space(3))) unsigned int*)l, 16, 0, 0);
}

__device__ __forceinline__ ushort4 cvt4(const float4 f) {
  __bf16 t[4] = {(__bf16)f.x, (__bf16)f.y, (__bf16)f.z, (__bf16)f.w};
  return *(const ushort4*)t;
}

// One-shot fp32 -> bf16 conversion of x, Wq|Wk|Wv (stacked into Wcat), Wo,
// plus fp32 bias packing bq|bk|bv -> bcat. 4 elems/thread.
__global__ __launch_bounds__(256)
void cvt_kernel(const float* __restrict__ x,
                const float* __restrict__ wq, const float* __restrict__ wk,
                const float* __restrict__ wv, const float* __restrict__ wo,
                const float* __restrict__ bq, const float* __restrict__ bk,
                const float* __restrict__ bv,
                __bf16* __restrict__ xb, __bf16* __restrict__ Wcat,
                __bf16* __restrict__ Wob, float* __restrict__ bcat)
{
  const int NX4 = 2097152;   // 8388608/4
  const int NW4 = 262144;    // 1048576/4
  int g = blockIdx.x * 256 + threadIdx.x;
  if (g < NX4) {
    *(ushort4*)(xb + (size_t)g * 4) = cvt4(*(const float4*)(x + (size_t)g * 4));
    return;
  }
  g -= NX4;
  if (g < 3 * NW4) {   // Wcat = [Wq; Wk; Wv] row-stacked
    const float* src = (g < NW4) ? wq : (g < 2 * NW4) ? wk : wv;
    const int gg = (g < NW4) ? g : (g < 2 * NW4) ? g - NW4 : g - 2 * NW4;
    *(ushort4*)(Wcat + (size_t)g * 4) = cvt4(*(const float4*)(src + (size_t)gg * 4));
    return;
  }
  g -= 3 * NW4;
  if (g < NW4) {
    *(ushort4*)(Wob + (size_t)g * 4) = cvt4(*(const float4*)(wo + (size_t)g * 4));
    return;
  }
  g -= NW4;
  if (g < 768) {       // bcat = [bq; bk; bv] fp32
    const float* src = (g < 256) ? bq : (g < 512) ? bk : bv;
    *(float4*)(bcat + (size_t)g * 4) = *(const float4*)(src + (size_t)(g & 255) * 4);
  }
}

// Fused QKV: C[8192,3072] = xb @ Wcat^T + bcat, all bf16, global_load_lds staging.
// n<1024 -> Q (scaled by SCL*log2e) BHSD; n<2048 -> K BHSD; else -> V^T BHDS.
__global__ __launch_bounds__(256)
void gemm_qkv_kernel(const __bf16* __restrict__ A, const __bf16* __restrict__ W,
                     const float* __restrict__ bcat,
                     __bf16* __restrict__ Qb, __bf16* __restrict__ Kb,
                     __bf16* __restrict__ Vb)
{
  __shared__ __attribute__((aligned(16))) __bf16 As[128 * 32];
  __shared__ __attribute__((aligned(16))) __bf16 Ws[128 * 32];
  const int tid  = threadIdx.x;
  const int wave = tid >> 6, lane = tid & 63;
  const int l15  = lane & 15, quad = lane >> 4;
  const int wm   = wave >> 1, wn = wave & 1;
  const int bm   = blockIdx.y * 128;
  const int bn   = blockIdx.x * 128;        // 0..2944
  const int widx = bn >> 10;                // 0=Q 1=K 2=V (block-uniform)
  const float QS = 0.180336880f;            // (1/sqrt(64)) * log2(e)

  floatx4 acc[4][4];
#pragma unroll
  for (int i = 0; i < 4; ++i)
#pragma unroll
    for (int j = 0; j < 4; ++j) acc[i][j] = (floatx4){0.f, 0.f, 0.f, 0.f};

  const int srow = tid >> 2;          // 0..63
  const int scol = (tid & 3) << 3;    // 0,8,16,24
  const __bf16* Ag = A + (size_t)(bm + srow) * 1024 + scol;
  const __bf16* Wg = W + (size_t)(bn + srow) * 1024 + scol;
  __bf16* AsD = As + tid * 8;
  __bf16* WsD = Ws + tid * 8;

  for (int k0 = 0; k0 < 1024; k0 += 32) {
    __syncthreads();
    async_cp16(Ag + k0,             AsD);
    async_cp16(Ag + k0 + 64 * 1024, AsD + 2048);
    async_cp16(Wg + k0,             WsD);
    async_cp16(Wg + k0 + 64 * 1024, WsD + 2048);
    __syncthreads();
    short8 af[4], wf[4];
#pragma unroll
    for (int mi = 0; mi < 4; ++mi)
      af[mi] = *(const short8*)(As + ((wm * 64 + mi * 16 + l15) << 5) + (quad << 3));
#pragma unroll
    for (int ni = 0; ni < 4; ++ni)
      wf[ni] = *(const short8*)(Ws + ((wn * 64 + ni * 16 + l15) << 5) + (quad << 3));
#pragma unroll
    for (int mi = 0; mi < 4; ++mi)
#pragma unroll
      for (int ni = 0; ni < 4; ++ni)
        acc[mi][ni] = __builtin_amdgcn_mfma_f32_16x16x32_bf16(af[mi], wf[ni], acc[mi][ni], 0, 0, 0);
  }

#pragma unroll
  for (int ni = 0; ni < 4; ++ni) {
    const int n  = bn + wn * 64 + ni * 16 + l15;
    const float bvb = bcat[n];
    const int np = n & 1023;
    const int h = np >> 6, d = np & 63;
#pragma unroll
    for (int mi = 0; mi < 4; ++mi) {
      const int m0 = bm + wm * 64 + mi * 16 + quad * 4;
      const int b = m0 >> 11, s0 = m0 & 2047;
      floatx4 v = acc[mi][ni];
      if (widx == 0) {
        const size_t base = (size_t)(b * 16 + h) * (S_ * 64) + d;
#pragma unroll
        for (int r = 0; r < 4; ++r)
          Qb[base + (size_t)(s0 + r) * 64] = (__bf16)((v[r] + bvb) * QS);
      } else if (widx == 1) {
        const size_t base = (size_t)(b * 16 + h) * (S_ * 64) + d;
#pragma unroll
        for (int r = 0; r < 4; ++r)
          Kb[base + (size_t)(s0 + r) * 64] = (__bf16)(v[r] + bvb);
      } else {
        const size_t base = ((size_t)(b * 16 + h) * 64 + d) * S_ + s0;
        union { ushort4 u4; unsigned short u[4]; } pk;
#pragma unroll
        for (int r = 0; r < 4; ++r) {
          __bf16 hv = (__bf16)(v[r] + bvb);
          pk.u[r] = *(unsigned short*)&hv;
        }
        *(ushort4*)(Vb + base) = pk.u4;    // 8B aligned: s0 % 4 == 0
      }
    }
  }
}

// Flash attention, causal, exp2-domain (Q pre-scaled by SCL*log2e).
// Grid (bh=64, qtA=16): bh fastest -> XCD = bh%8, all 16 blocks of a head share
// one XCD L2 (K+V/head = 4 MB = one L2). Block merges q-tiles {qtA, 31-qtA} in
// ONE k-loop: each staged K/V tile feeds both (stages qtH+1, computes 33).
// Register prefetch of tile kt+1 overlaps the (barrier-free) compute phase.
// Ps is per-wave private LDS (in-order DS) -> no barrier before PV reads.
// Output IN-PLACE over Q (block-owned rows).
__global__ __launch_bounds__(256, 4)
void attn_kernel(__bf16* __restrict__ Q, const __bf16* __restrict__ K,
                 const __bf16* __restrict__ Vt)
{
  __shared__ __attribute__((aligned(16))) __bf16 Ks[64 * 72];
  __shared__ __attribute__((aligned(16))) __bf16 Vs[80 * 72];   // [d][s]; rows 64..79: ones/zeros
  __shared__ __attribute__((aligned(16))) __bf16 Ps[4][16 * 72];

  const int tid  = threadIdx.x;
  const int wave = tid >> 6, lane = tid & 63;
  const int l15  = lane & 15, quad = lane >> 4;
  const int bh   = blockIdx.x;
  const int qtL  = blockIdx.y;             // 0..15
  const int qtH  = 31 - qtL;               // 16..31
  const size_t hb = (size_t)bh * (S_ * 64);
  const float MASKV = -1.0e30f;

  // l-column trick: Vs row 64 = ones, rows 65..79 = zeros (persist across tiles)
  for (int idx = tid; idx < 16 * 72; idx += 256)
    Vs[64 * 72 + idx] = (idx < 72) ? (__bf16)1.0f : (__bf16)0.0f;

  const int qwL = qtL * 64 + wave * 16;
  const int qwH = qtH * 64 + wave * 16;
  short8 aqL[2], aqH[2];
#pragma unroll
  for (int kk = 0; kk < 2; ++kk) {
    aqL[kk] = *(const short8*)(Q + hb + (size_t)(qwL + l15) * 64 + kk * 32 + quad * 8);
    aqH[kk] = *(const short8*)(Q + hb + (size_t)(qwH + l15) * 64 + kk * 32 + quad * 8);
  }

  floatx4 oaccL[4], oaccH[4];
#pragma unroll
  for (int j = 0; j < 4; ++j) {
    oaccL[j] = (floatx4){0.f, 0.f, 0.f, 0.f};
    oaccH[j] = (floatx4){0.f, 0.f, 0.f, 0.f};
  }
  floatx4 laccL = (floatx4){0.f, 0.f, 0.f, 0.f};
  floatx4 laccH = (floatx4){0.f, 0.f, 0.f, 0.f};
  float mstL[4], mstH[4];
#pragma unroll
  for (int r = 0; r < 4; ++r) { mstL[r] = MASKV; mstH[r] = MASKV; }

  // staging map: 256 threads move one 64x64 tile of K and of V^T per k-step
  const int sr = tid >> 3;            // 0..31
  const int sc = (tid & 7) << 3;      // 0..56
  uint4 kreg[2], vreg[2];
#pragma unroll
  for (int p = 0; p < 2; ++p) {       // prefetch tile 0
    const int row = sr + p * 32;
    kreg[p] = *(const uint4*)(K  + hb + (size_t)(0 * 64 + row) * 64 + sc);
    vreg[p] = *(const uint4*)(Vt + hb + (size_t)row * S_ + 0 * 64 + sc);
  }

  // per-tile compute (QK^T -> online softmax -> Ps -> PV + l-MFMA)
  auto tile = [&](const short8* aq, floatx4* oacc, floatx4& lacc, float* mst,
                  const int qw, const int kt, const bool domask) {
    floatx4 sacc[4];
#pragma unroll
    for (int j = 0; j < 4; ++j) sacc[j] = (floatx4){0.f, 0.f, 0.f, 0.f};
#pragma unroll
    for (int kk = 0; kk < 2; ++kk) {
      short8 bk[4];
#pragma unroll
      for (int ni = 0; ni < 4; ++ni)
        bk[ni] = *(const short8*)(&Ks[(ni * 16 + l15) * 72 + kk * 32 + quad * 8]);
#pragma unroll
      for (int ni = 0; ni < 4; ++ni)
        sacc[ni] = __builtin_amdgcn_mfma_f32_16x16x32_bf16(aq[kk], bk[ni], sacc[ni], 0, 0, 0);
    }
    const int sc0 = kt * 64 + l15;
#pragma unroll
    for (int r = 0; r < 4; ++r) {
      const int qg = qw + quad * 4 + r;
      float z[4];
#pragma unroll
      for (int ni = 0; ni < 4; ++ni) {
        float zz = sacc[ni][r];
        if (domask && (sc0 + ni * 16 > qg)) zz = MASKV;   // causal: key > query
        z[ni] = zz;
      }
      float tmax = fmaxf(fmaxf(z[0], z[1]), fmaxf(z[2], z[3]));
      tmax = fmaxf(tmax, __shfl_xor(tmax, 1));
      tmax = fmaxf(tmax, __shfl_xor(tmax, 2));
      tmax = fmaxf(tmax, __shfl_xor(tmax, 4));
      tmax = fmaxf(tmax, __shfl_xor(tmax, 8));
      const float mold = mst[r];
      const float mnew = fmaxf(mold, tmax);
      mst[r] = mnew;
      const float alpha = EXP2F(mold - mnew);
#pragma unroll
      for (int ni = 0; ni < 4; ++ni) {
        const float p = EXP2F(z[ni] - mnew);
        Ps[wave][(quad * 4 + r) * 72 + ni * 16 + l15] = (__bf16)p;
      }
#pragma unroll
      for (int ni = 0; ni < 4; ++ni) oacc[ni][r] *= alpha;
      lacc[r] *= alpha;
    }
    // per-wave Ps round-trip: DS ops of one wave are in-order; no barrier needed
#pragma unroll
    for (int kk = 0; kk < 2; ++kk) {
      const short8 ap = *(const short8*)(&Ps[wave][l15 * 72 + kk * 32 + quad * 8]);
      short8 bv[4];
#pragma unroll
      for (int ni = 0; ni < 4; ++ni)
        bv[ni] = *(const short8*)(&Vs[(ni * 16 + l15) * 72 + kk * 32 + quad * 8]);
      const short8 bl = *(const short8*)(&Vs[(64 + l15) * 72 + kk * 32 + quad * 8]);
#pragma unroll
      for (int ni = 0; ni < 4; ++ni)
        oacc[ni] = __builtin_amdgcn_mfma_f32_16x16x32_bf16(ap, bv[ni], oacc[ni], 0, 0, 0);
      lacc = __builtin_amdgcn_mfma_f32_16x16x32_bf16(ap, bl, lacc, 0, 0, 0);
    }
  };

  for (int kt = 0; kt <= qtH; ++kt) {
    __syncthreads();                  // prev-tile LDS reads done; prefetch drained
#pragma unroll
    for (int p = 0; p < 2; ++p) {
      const int row = sr + p * 32;
      *(uint4*)(&Ks[row * 72 + sc]) = kreg[p];
      *(uint4*)(&Vs[row * 72 + sc]) = vreg[p];
    }
    __syncthreads();                  // staged tile visible
    if (kt < qtH) {                   // prefetch kt+1 during compute
      const int kn = kt + 1;
#pragma unroll
      for (int p = 0; p < 2; ++p) {
        const int row = sr + p * 32;
        kreg[p] = *(const uint4*)(K  + hb + (size_t)(kn * 64 + row) * 64 + sc);
        vreg[p] = *(const uint4*)(Vt + hb + (size_t)row * S_ + kn * 64 + sc);
      }
    }
    tile(aqH, oaccH, laccH, mstH, qwH, kt, kt == qtH);
    if (kt <= qtL)
      tile(aqL, oaccL, laccL, mstL, qwL, kt, kt == qtL);
  }

  // epilogue: O /= l (l in lanes l15==0 of each quad-group), in-place over Q
#pragma unroll
  for (int r = 0; r < 4; ++r) {
    const float lvH = __shfl(laccH[r], lane & 48);
    const float lvL = __shfl(laccL[r], lane & 48);
    const float invH = 1.0f / fmaxf(lvH, 1e-20f);
    const float invL = 1.0f / fmaxf(lvL, 1e-20f);
    const size_t rowH = hb + (size_t)(qwH + quad * 4 + r) * 64;
    const size_t rowL = hb + (size_t)(qwL + quad * 4 + r) * 64;
#pragma unroll
    for (int ni = 0; ni < 4; ++ni) {
      Q[rowH + ni * 16 + l15] = (__bf16)(oaccH[ni][r] * invH);
      Q[rowL + ni * 16 + l15] = (__bf16)(oaccL[ni][r] * invL);
    }
  }
}

// Final projection: A = attn output (bf16, BHSD gather), W = Wob bf16,
// bias fp32, out fp32 row-major. global_load_lds staging.
__global__ __launch_bounds__(256)
void gemm_o_kernel(const __bf16* __restrict__ A, const __bf16* __restrict__ W,
                   const float* __restrict__ bias, float* __restrict__ out)
{
  __shared__ __attribute__((aligned(16))) __bf16 As[128 * 32];
  __shared__ __attribute__((aligned(16))) __bf16 Ws[128 * 32];
  const int tid  = threadIdx.x;
  const int wave = tid >> 6, lane = tid & 63;
  const int l15  = lane & 15, quad = lane >> 4;
  const int wm   = wave >> 1, wn = wave & 1;
  const int bm   = blockIdx.y * 128;
  const int bn   = blockIdx.x * 128;

  floatx4 acc[4][4];
#pragma unroll
  for (int i = 0; i < 4; ++i)
#pragma unroll
    for (int j = 0; j < 4; ++j) acc[i][j] = (floatx4){0.f, 0.f, 0.f, 0.f};

  const int srow = tid >> 2;
  const int scol = (tid & 3) << 3;
  const __bf16* Wg = W + (size_t)(bn + srow) * 1024 + scol;
  const int bb = bm >> 11;                 // batch
  const int ss = (bm & 2047) + srow;       // seq
  __bf16* AsD = As + tid * 8;
  __bf16* WsD = Ws + tid * 8;

  for (int k0 = 0; k0 < 1024; k0 += 32) {
    const int c = k0 + scol, h = c >> 6, dd = c & 63;  // 8 elems never cross a head
    const __bf16* pa0 = A + (((size_t)(bb * 16 + h) * S_) + ss) * 64 + dd;
    __syncthreads();
    async_cp16(pa0,           AsD);
    async_cp16(pa0 + 64 * 64, AsD + 2048);             // s -> s+64
    async_cp16(Wg + k0,             WsD);
    async_cp16(Wg + k0 + 64 * 1024, WsD + 2048);
    __syncthreads();

    short8 af[4], wf[4];
#pragma unroll
    for (int mi = 0; mi < 4; ++mi)
      af[mi] = *(const short8*)(As + ((wm * 64 + mi * 16 + l15) << 5) + (quad << 3));
#pragma unroll
    for (int ni = 0; ni < 4; ++ni)
      wf[ni] = *(const short8*)(Ws + ((wn * 64 + ni * 16 + l15) << 5) + (quad << 3));
#pragma unroll
    for (int mi = 0; mi < 4; ++mi)
#pragma unroll
      for (int ni = 0; ni < 4; ++ni)
        acc[mi][ni] = __builtin_amdgcn_mfma_f32_16x16x32_bf16(af[mi], wf[ni], acc[mi][ni], 0, 0, 0);
  }

#pragma unroll
  for (int ni = 0; ni < 4; ++ni) {
    const int n = bn + wn * 64 + ni * 16 + l15;
    const float bvb = bias[n];
#pragma unroll
    for (int mi = 0; mi < 4; ++mi) {
      const int m0 = bm + wm * 64 + mi * 16 + quad * 4;
      floatx4 v = acc[mi][ni];
#pragma unroll
      for (int r = 0; r < 4; ++r)
        out[(size_t)(m0 + r) * 1024 + n] = v[r] + bvb;
    }
  }
}

extern "C" void kernel_launch(void* const* d_in, const int* in_sizes, int n_in,
                              void* d_out, int out_size, void* d_ws, size_t ws_size,
                              hipStream_t stream) {
  const float* x  = (const float*)d_in[0];
  const float* Wq = (const float*)d_in[1];
  const float* bq = (const float*)d_in[2];
  const float* Wk = (const float*)d_in[3];
  const float* bk = (const float*)d_in[4];
  const float* Wv = (const float*)d_in[5];
  const float* bv = (const float*)d_in[6];
  const float* Wo = (const float*)d_in[7];
  const float* bo = (const float*)d_in[8];
  // d_in[9] = causal_mask (int32) — causality implemented analytically, unused.

  const size_t BUF = (size_t)B_ * NH_ * S_ * HD_;   // 8388608 elems
  __bf16* ws   = (__bf16*)d_ws;                     // ws usage: ~42 MB
  __bf16* xb   = ws;                                // 8388608  (16.8 MB)
  __bf16* Wcat = ws + 8388608;                      // 3145728  (6 MB)
  __bf16* Wob  = ws + 11534336;                     // 1048576  (2 MB)
  __bf16* Qb   = ws + 12582912;                     // 8388608  (16.8 MB)
  float*  bcat = (float*)(ws + 20971520);           // 3072 fp32 (12 KB)
  __bf16* Kb   = (__bf16*)d_out;                    // d_out reused as K+V^T
  __bf16* Vb   = (__bf16*)d_out + BUF;              // scratch until attn done

  dim3 blk(256);
  cvt_kernel<<<12291, blk, 0, stream>>>(x, Wq, Wk, Wv, Wo, bq, bk, bv,
                                        xb, Wcat, Wob, bcat);
  gemm_qkv_kernel<<<dim3(24, 64), blk, 0, stream>>>(xb, Wcat, bcat, Qb, Kb, Vb);
  attn_kernel<<<dim3(64, 16), blk, 0, stream>>>(Qb, Kb, Vb);
  gemm_o_kernel<<<dim3(8, 64), blk, 0, stream>>>(Qb, Wob, bo, (float*)d_out);
}

// Round 8
// 372.368 us; speedup vs baseline: 1.4700x; 1.4700x over previous
//
#include <hip/hip_runtime.h>
#include <hip/hip_bf16.h>

typedef __attribute__((ext_vector_type(8))) short short8;
typedef __attribute__((ext_vector_type(4))) float floatx4;

#define B_    4
#define S_    2048
#define EMB_  1024
#define NH_   16
#define HD_   64

#define EXP2F(x) exp2f(x)

__device__ __forceinline__ void async_cp16(const void* g, void* l) {
  __builtin_amdgcn_global_load_lds(
      (const __attribute__((address_space(1))) unsigned int*)g,
      (__attribute__((address_space(3))) unsigned int*)l, 16, 0, 0);
}

__device__ __forceinline__ ushort4 cvt4(const float4 f) {
  __bf16 t[4] = {(__bf16)f.x, (__bf16)f.y, (__bf16)f.z, (__bf16)f.w};
  return *(const ushort4*)t;
}

// One-shot fp32 -> bf16 conversion of x, Wq|Wk|Wv (stacked into Wcat), Wo,
// plus fp32 bias packing bq|bk|bv -> bcat. 4 elems/thread.
__global__ __launch_bounds__(256)
void cvt_kernel(const float* __restrict__ x,
                const float* __restrict__ wq, const float* __restrict__ wk,
                const float* __restrict__ wv, const float* __restrict__ wo,
                const float* __restrict__ bq, const float* __restrict__ bk,
                const float* __restrict__ bv,
                __bf16* __restrict__ xb, __bf16* __restrict__ Wcat,
                __bf16* __restrict__ Wob, float* __restrict__ bcat)
{
  const int NX4 = 2097152;   // 8388608/4
  const int NW4 = 262144;    // 1048576/4
  int g = blockIdx.x * 256 + threadIdx.x;
  if (g < NX4) {
    *(ushort4*)(xb + (size_t)g * 4) = cvt4(*(const float4*)(x + (size_t)g * 4));
    return;
  }
  g -= NX4;
  if (g < 3 * NW4) {   // Wcat = [Wq; Wk; Wv] row-stacked
    const float* src = (g < NW4) ? wq : (g < 2 * NW4) ? wk : wv;
    const int gg = (g < NW4) ? g : (g < 2 * NW4) ? g - NW4 : g - 2 * NW4;
    *(ushort4*)(Wcat + (size_t)g * 4) = cvt4(*(const float4*)(src + (size_t)gg * 4));
    return;
  }
  g -= 3 * NW4;
  if (g < NW4) {
    *(ushort4*)(Wob + (size_t)g * 4) = cvt4(*(const float4*)(wo + (size_t)g * 4));
    return;
  }
  g -= NW4;
  if (g < 768) {       // bcat = [bq; bk; bv] fp32
    const float* src = (g < 256) ? bq : (g < 512) ? bk : bv;
    *(float4*)(bcat + (size_t)g * 4) = *(const float4*)(src + (size_t)(g & 255) * 4);
  }
}

// Fused QKV: C[8192,3072] = xb @ Wcat^T + bcat, all bf16, global_load_lds staging.
// n<1024 -> Q (scaled by SCL*log2e) BHSD; n<2048 -> K BHSD; else -> V^T BHDS.
__global__ __launch_bounds__(256)
void gemm_qkv_kernel(const __bf16* __restrict__ A, const __bf16* __restrict__ W,
                     const float* __restrict__ bcat,
                     __bf16* __restrict__ Qb, __bf16* __restrict__ Kb,
                     __bf16* __restrict__ Vb)
{
  __shared__ __attribute__((aligned(16))) __bf16 As[128 * 32];
  __shared__ __attribute__((aligned(16))) __bf16 Ws[128 * 32];
  const int tid  = threadIdx.x;
  const int wave = tid >> 6, lane = tid & 63;
  const int l15  = lane & 15, quad = lane >> 4;
  const int wm   = wave >> 1, wn = wave & 1;
  const int bm   = blockIdx.y * 128;
  const int bn   = blockIdx.x * 128;        // 0..2944
  const int widx = bn >> 10;                // 0=Q 1=K 2=V (block-uniform)
  const float QS = 0.180336880f;            // (1/sqrt(64)) * log2(e)

  floatx4 acc[4][4];
#pragma unroll
  for (int i = 0; i < 4; ++i)
#pragma unroll
    for (int j = 0; j < 4; ++j) acc[i][j] = (floatx4){0.f, 0.f, 0.f, 0.f};

  const int srow = tid >> 2;          // 0..63
  const int scol = (tid & 3) << 3;    // 0,8,16,24
  const __bf16* Ag = A + (size_t)(bm + srow) * 1024 + scol;
  const __bf16* Wg = W + (size_t)(bn + srow) * 1024 + scol;
  __bf16* AsD = As + tid * 8;
  __bf16* WsD = Ws + tid * 8;

  for (int k0 = 0; k0 < 1024; k0 += 32) {
    __syncthreads();
    async_cp16(Ag + k0,             AsD);
    async_cp16(Ag + k0 + 64 * 1024, AsD + 2048);
    async_cp16(Wg + k0,             WsD);
    async_cp16(Wg + k0 + 64 * 1024, WsD + 2048);
    __syncthreads();
    short8 af[4], wf[4];
#pragma unroll
    for (int mi = 0; mi < 4; ++mi)
      af[mi] = *(const short8*)(As + ((wm * 64 + mi * 16 + l15) << 5) + (quad << 3));
#pragma unroll
    for (int ni = 0; ni < 4; ++ni)
      wf[ni] = *(const short8*)(Ws + ((wn * 64 + ni * 16 + l15) << 5) + (quad << 3));
#pragma unroll
    for (int mi = 0; mi < 4; ++mi)
#pragma unroll
      for (int ni = 0; ni < 4; ++ni)
        acc[mi][ni] = __builtin_amdgcn_mfma_f32_16x16x32_bf16(af[mi], wf[ni], acc[mi][ni], 0, 0, 0);
  }

#pragma unroll
  for (int ni = 0; ni < 4; ++ni) {
    const int n  = bn + wn * 64 + ni * 16 + l15;
    const float bvb = bcat[n];
    const int np = n & 1023;
    const int h = np >> 6, d = np & 63;
#pragma unroll
    for (int mi = 0; mi < 4; ++mi) {
      const int m0 = bm + wm * 64 + mi * 16 + quad * 4;
      const int b = m0 >> 11, s0 = m0 & 2047;
      floatx4 v = acc[mi][ni];
      if (widx == 0) {
        const size_t base = (size_t)(b * 16 + h) * (S_ * 64) + d;
#pragma unroll
        for (int r = 0; r < 4; ++r)
          Qb[base + (size_t)(s0 + r) * 64] = (__bf16)((v[r] + bvb) * QS);
      } else if (widx == 1) {
        const size_t base = (size_t)(b * 16 + h) * (S_ * 64) + d;
#pragma unroll
        for (int r = 0; r < 4; ++r)
          Kb[base + (size_t)(s0 + r) * 64] = (__bf16)(v[r] + bvb);
      } else {
        const size_t base = ((size_t)(b * 16 + h) * 64 + d) * S_ + s0;
        union { ushort4 u4; unsigned short u[4]; } pk;
#pragma unroll
        for (int r = 0; r < 4; ++r) {
          __bf16 hv = (__bf16)(v[r] + bvb);
          pk.u[r] = *(unsigned short*)&hv;
        }
        *(ushort4*)(Vb + base) = pk.u4;    // 8B aligned: s0 % 4 == 0
      }
    }
  }
}

// Flash attention, causal, exp2-domain (Q pre-scaled by SCL*log2e).
// Grid (bh=64, qtA=16): bh fastest -> XCD = bh%8; per-bh K+V = 512 KB, so each
// XCD's 8 bh values = 4 MB = its L2 -> tile re-reads hit L2, not HBM.
// Block processes q-tiles {qtA, 31-qtA} sequentially (33 k-tiles, balanced).
// Each wave owns 16 q-rows; Q fragments in registers (no Qs LDS).
// K/V tile kt+1 prefetched into registers during compute (no spill-prone lambda;
// all accumulators are plain locals -> SROA keeps them in VGPRs).
// l computed via MFMA ones-column (Vs row 64 = ones, rows 65..79 = 0).
// Ps is per-wave private LDS (DS in-order within a wave) -> no barrier before PV.
// Output IN-PLACE over Q (block-owned rows).
__global__ __launch_bounds__(256, 4)
void attn_kernel(__bf16* __restrict__ Q, const __bf16* __restrict__ K,
                 const __bf16* __restrict__ Vt)
{
  __shared__ __attribute__((aligned(16))) __bf16 Ks[64 * 72];
  __shared__ __attribute__((aligned(16))) __bf16 Vs[80 * 72];
  __shared__ __attribute__((aligned(16))) __bf16 Ps[4][16 * 72];

  const int tid  = threadIdx.x;
  const int wave = tid >> 6, lane = tid & 63;
  const int l15  = lane & 15, quad = lane >> 4;
  const int bh   = blockIdx.x;             // fastest -> XCD = bh % 8
  const int qtA  = blockIdx.y;             // 0..15
  const size_t hb = (size_t)bh * (S_ * 64);
  const float MASKV = -1.0e30f;

  // one-time init: Vs row 64 = ones (l-column), rows 65..79 = zeros
  for (int idx = tid; idx < 16 * 72; idx += 256)
    Vs[64 * 72 + idx] = (idx < 72) ? (__bf16)1.0f : (__bf16)0.0f;

  // staging map: 256 threads move one 64x64 tile of K and of V^T per k-step
  const int sr = tid >> 3;            // 0..31
  const int sc = (tid & 7) << 3;      // 0..56

  for (int qsel = 0; qsel < 2; ++qsel) {
    const int qt = qsel ? (31 - qtA) : qtA;
    const int q0 = qt * 64;
    const int qw = q0 + wave * 16;          // wave's first q row

    // Q fragments in registers: A[m=l15][k=kk*32+quad*8+j]
    short8 aq[2];
#pragma unroll
    for (int kk = 0; kk < 2; ++kk)
      aq[kk] = *(const short8*)(Q + hb + (size_t)(qw + l15) * 64 + kk * 32 + quad * 8);

    floatx4 oacc[4];
#pragma unroll
    for (int j = 0; j < 4; ++j) oacc[j] = (floatx4){0.f, 0.f, 0.f, 0.f};
    floatx4 lacc = (floatx4){0.f, 0.f, 0.f, 0.f};
    float mst[4];
#pragma unroll
    for (int r = 0; r < 4; ++r) mst[r] = MASKV;

    // prefetch tile 0 into registers
    uint4 kreg[2], vreg[2];
#pragma unroll
    for (int p = 0; p < 2; ++p) {
      const int row = sr + p * 32;
      kreg[p] = *(const uint4*)(K  + hb + (size_t)row * 64 + sc);
      vreg[p] = *(const uint4*)(Vt + hb + (size_t)row * S_ + sc);
    }

    for (int kt = 0; kt <= qt; ++kt) {
      __syncthreads();                // prev tile's LDS reads done
#pragma unroll
      for (int p = 0; p < 2; ++p) {
        const int row = sr + p * 32;
        *(uint4*)(&Ks[row * 72 + sc]) = kreg[p];
        *(uint4*)(&Vs[row * 72 + sc]) = vreg[p];
      }
      __syncthreads();                // staged tile visible
      if (kt < qt) {                  // prefetch kt+1; flies during compute
        const int kn = kt + 1;
#pragma unroll
        for (int p = 0; p < 2; ++p) {
          const int row = sr + p * 32;
          kreg[p] = *(const uint4*)(K  + hb + (size_t)(kn * 64 + row) * 64 + sc);
          vreg[p] = *(const uint4*)(Vt + hb + (size_t)row * S_ + kn * 64 + sc);
        }
      }

      // S = Q K^T (pre-scaled by SCL*log2e)
      floatx4 sacc[4];
#pragma unroll
      for (int j = 0; j < 4; ++j) sacc[j] = (floatx4){0.f, 0.f, 0.f, 0.f};
#pragma unroll
      for (int kk = 0; kk < 2; ++kk) {
        short8 bk[4];
#pragma unroll
        for (int ni = 0; ni < 4; ++ni)
          bk[ni] = *(const short8*)(&Ks[(ni * 16 + l15) * 72 + kk * 32 + quad * 8]);
#pragma unroll
        for (int ni = 0; ni < 4; ++ni)
          sacc[ni] = __builtin_amdgcn_mfma_f32_16x16x32_bf16(aq[kk], bk[ni], sacc[ni], 0, 0, 0);
      }

      // online softmax (exp2 domain). Mask only on the diagonal tile.
      const bool needmask = (kt == qt);
      const int sc0 = kt * 64 + l15;
#pragma unroll
      for (int r = 0; r < 4; ++r) {
        const int qg = qw + quad * 4 + r;
        float z[4];
        if (needmask) {
#pragma unroll
          for (int ni = 0; ni < 4; ++ni) {
            float zz = sacc[ni][r];
            if (sc0 + ni * 16 > qg) zz = MASKV;   // causal: key > query
            z[ni] = zz;
          }
        } else {
#pragma unroll
          for (int ni = 0; ni < 4; ++ni) z[ni] = sacc[ni][r];
        }
        float tmax = fmaxf(fmaxf(z[0], z[1]), fmaxf(z[2], z[3]));
        tmax = fmaxf(tmax, __shfl_xor(tmax, 1));
        tmax = fmaxf(tmax, __shfl_xor(tmax, 2));
        tmax = fmaxf(tmax, __shfl_xor(tmax, 4));
        tmax = fmaxf(tmax, __shfl_xor(tmax, 8));
        const float mold = mst[r];
        const float mnew = fmaxf(mold, tmax);
        mst[r] = mnew;
        const float alpha = EXP2F(mold - mnew);
#pragma unroll
        for (int ni = 0; ni < 4; ++ni) {
          const float p = EXP2F(z[ni] - mnew);
          Ps[wave][(quad * 4 + r) * 72 + ni * 16 + l15] = (__bf16)p;
        }
#pragma unroll
        for (int ni = 0; ni < 4; ++ni) oacc[ni][r] *= alpha;
        lacc[r] *= alpha;
      }

      // per-wave Ps round-trip: DS ops of one wave are in-order; no barrier.
      // O += P(16x64) @ V(64x64); l += P @ ones (Vs row 64)
#pragma unroll
      for (int kk = 0; kk < 2; ++kk) {
        const short8 ap = *(const short8*)(&Ps[wave][l15 * 72 + kk * 32 + quad * 8]);
        short8 bv[4];
#pragma unroll
        for (int ni = 0; ni < 4; ++ni)
          bv[ni] = *(const short8*)(&Vs[(ni * 16 + l15) * 72 + kk * 32 + quad * 8]);
        const short8 bl = *(const short8*)(&Vs[(64 + l15) * 72 + kk * 32 + quad * 8]);
#pragma unroll
        for (int ni = 0; ni < 4; ++ni)
          oacc[ni] = __builtin_amdgcn_mfma_f32_16x16x32_bf16(ap, bv[ni], oacc[ni], 0, 0, 0);
        lacc = __builtin_amdgcn_mfma_f32_16x16x32_bf16(ap, bl, lacc, 0, 0, 0);
      }
    }

    // epilogue: O /= l (l in lanes l15==0 of each quad-group), in-place over Q
#pragma unroll
    for (int r = 0; r < 4; ++r) {
      const float lv  = __shfl(lacc[r], lane & 48);   // from lane quad*16
      const float inv = 1.0f / fmaxf(lv, 1e-20f);
      const int qg = qw + quad * 4 + r;
      const size_t rowb = hb + (size_t)qg * 64;
#pragma unroll
      for (int ni = 0; ni < 4; ++ni)
        Q[rowb + ni * 16 + l15] = (__bf16)(oacc[ni][r] * inv);
    }
  }
}

// Final projection: A = attn output (bf16, BHSD gather), W = Wob bf16,
// bias fp32, out fp32 row-major. global_load_lds staging.
__global__ __launch_bounds__(256)
void gemm_o_kernel(const __bf16* __restrict__ A, const __bf16* __restrict__ W,
                   const float* __restrict__ bias, float* __restrict__ out)
{
  __shared__ __attribute__((aligned(16))) __bf16 As[128 * 32];
  __shared__ __attribute__((aligned(16))) __bf16 Ws[128 * 32];
  const int tid  = threadIdx.x;
  const int wave = tid >> 6, lane = tid & 63;
  const int l15  = lane & 15, quad = lane >> 4;
  const int wm   = wave >> 1, wn = wave & 1;
  const int bm   = blockIdx.y * 128;
  const int bn   = blockIdx.x * 128;

  floatx4 acc[4][4];
#pragma unroll
  for (int i = 0; i < 4; ++i)
#pragma unroll
    for (int j = 0; j < 4; ++j) acc[i][j] = (floatx4){0.f, 0.f, 0.f, 0.f};

  const int srow = tid >> 2;
  const int scol = (tid & 3) << 3;
  const __bf16* Wg = W + (size_t)(bn + srow) * 1024 + scol;
  const int bb = bm >> 11;                 // batch
  const int ss = (bm & 2047) + srow;       // seq
  __bf16* AsD = As + tid * 8;
  __bf16* WsD = Ws + tid * 8;

  for (int k0 = 0; k0 < 1024; k0 += 32) {
    const int c = k0 + scol, h = c >> 6, dd = c & 63;  // 8 elems never cross a head
    const __bf16* pa0 = A + (((size_t)(bb * 16 + h) * S_) + ss) * 64 + dd;
    __syncthreads();
    async_cp16(pa0,           AsD);
    async_cp16(pa0 + 64 * 64, AsD + 2048);             // s -> s+64
    async_cp16(Wg + k0,             WsD);
    async_cp16(Wg + k0 + 64 * 1024, WsD + 2048);
    __syncthreads();

    short8 af[4], wf[4];
#pragma unroll
    for (int mi = 0; mi < 4; ++mi)
      af[mi] = *(const short8*)(As + ((wm * 64 + mi * 16 + l15) << 5) + (quad << 3));
#pragma unroll
    for (int ni = 0; ni < 4; ++ni)
      wf[ni] = *(const short8*)(Ws + ((wn * 64 + ni * 16 + l15) << 5) + (quad << 3));
#pragma unroll
    for (int mi = 0; mi < 4; ++mi)
#pragma unroll
      for (int ni = 0; ni < 4; ++ni)
        acc[mi][ni] = __builtin_amdgcn_mfma_f32_16x16x32_bf16(af[mi], wf[ni], acc[mi][ni], 0, 0, 0);
  }

#pragma unroll
  for (int ni = 0; ni < 4; ++ni) {
    const int n = bn + wn * 64 + ni * 16 + l15;
    const float bvb = bias[n];
#pragma unroll
    for (int mi = 0; mi < 4; ++mi) {
      const int m0 = bm + wm * 64 + mi * 16 + quad * 4;
      floatx4 v = acc[mi][ni];
#pragma unroll
      for (int r = 0; r < 4; ++r)
        out[(size_t)(m0 + r) * 1024 + n] = v[r] + bvb;
    }
  }
}

extern "C" void kernel_launch(void* const* d_in, const int* in_sizes, int n_in,
                              void* d_out, int out_size, void* d_ws, size_t ws_size,
                              hipStream_t stream) {
  const float* x  = (const float*)d_in[0];
  const float* Wq = (const float*)d_in[1];
  const float* bq = (const float*)d_in[2];
  const float* Wk = (const float*)d_in[3];
  const float* bk = (const float*)d_in[4];
  const float* Wv = (const float*)d_in[5];
  const float* bv = (const float*)d_in[6];
  const float* Wo = (const float*)d_in[7];
  const float* bo = (const float*)d_in[8];
  // d_in[9] = causal_mask (int32) — causality implemented analytically, unused.

  const size_t BUF = (size_t)B_ * NH_ * S_ * HD_;   // 8388608 elems
  __bf16* ws   = (__bf16*)d_ws;                     // ws usage: ~42 MB
  __bf16* xb   = ws;                                // 8388608  (16.8 MB)
  __bf16* Wcat = ws + 8388608;                      // 3145728  (6 MB)
  __bf16* Wob  = ws + 11534336;                     // 1048576  (2 MB)
  __bf16* Qb   = ws + 12582912;                     // 8388608  (16.8 MB)
  float*  bcat = (float*)(ws + 20971520);           // 3072 fp32 (12 KB)
  __bf16* Kb   = (__bf16*)d_out;                    // d_out reused as K+V^T
  __bf16* Vb   = (__bf16*)d_out + BUF;              // scratch until attn done

  dim3 blk(256);
  cvt_kernel<<<12291, blk, 0, stream>>>(x, Wq, Wk, Wv, Wo, bq, bk, bv,
                                        xb, Wcat, Wob, bcat);
  gemm_qkv_kernel<<<dim3(24, 64), blk, 0, stream>>>(xb, Wcat, bcat, Qb, Kb, Vb);
  attn_kernel<<<dim3(64, 16), blk, 0, stream>>>(Qb, Kb, Vb);
  gemm_o_kernel<<<dim3(8, 64), blk, 0, stream>>>(Qb, Wob, bo, (float*)d_out);
}

// Round 9
// 310.613 us; speedup vs baseline: 1.7623x; 1.1988x over previous
//
#include <hip/hip_runtime.h>
#include <hip/hip_bf16.h>

typedef __attribute__((ext_vector_type(8))) short short8;
typedef __attribute__((ext_vector_type(4))) float floatx4;

#define B_    4
#define S_    2048
#define EMB_  1024
#define NH_   16
#define HD_   64

#define EXP2F(x) exp2f(x)

__device__ __forceinline__ void async_cp16(const void* g, void* l) {
  __builtin_amdgcn_global_load_lds(
      (const __attribute__((address_space(1))) unsigned int*)g,
      (__attribute__((address_space(3))) unsigned int*)l, 16, 0, 0);
}

__device__ __forceinline__ ushort4 cvt4(const float4 f) {
  __bf16 t[4] = {(__bf16)f.x, (__bf16)f.y, (__bf16)f.z, (__bf16)f.w};
  return *(const ushort4*)t;
}

// One-shot fp32 -> bf16 conversion of x, Wq|Wk|Wv (stacked into Wcat), Wo,
// plus fp32 bias packing bq|bk|bv -> bcat. 4 elems/thread.
__global__ __launch_bounds__(256)
void cvt_kernel(const float* __restrict__ x,
                const float* __restrict__ wq, const float* __restrict__ wk,
                const float* __restrict__ wv, const float* __restrict__ wo,
                const float* __restrict__ bq, const float* __restrict__ bk,
                const float* __restrict__ bv,
                __bf16* __restrict__ xb, __bf16* __restrict__ Wcat,
                __bf16* __restrict__ Wob, float* __restrict__ bcat)
{
  const int NX4 = 2097152;   // 8388608/4
  const int NW4 = 262144;    // 1048576/4
  int g = blockIdx.x * 256 + threadIdx.x;
  if (g < NX4) {
    *(ushort4*)(xb + (size_t)g * 4) = cvt4(*(const float4*)(x + (size_t)g * 4));
    return;
  }
  g -= NX4;
  if (g < 3 * NW4) {   // Wcat = [Wq; Wk; Wv] row-stacked
    const float* src = (g < NW4) ? wq : (g < 2 * NW4) ? wk : wv;
    const int gg = (g < NW4) ? g : (g < 2 * NW4) ? g - NW4 : g - 2 * NW4;
    *(ushort4*)(Wcat + (size_t)g * 4) = cvt4(*(const float4*)(src + (size_t)gg * 4));
    return;
  }
  g -= 3 * NW4;
  if (g < NW4) {
    *(ushort4*)(Wob + (size_t)g * 4) = cvt4(*(const float4*)(wo + (size_t)g * 4));
    return;
  }
  g -= NW4;
  if (g < 768) {       // bcat = [bq; bk; bv] fp32
    const float* src = (g < 256) ? bq : (g < 512) ? bk : bv;
    *(float4*)(bcat + (size_t)g * 4) = *(const float4*)(src + (size_t)(g & 255) * 4);
  }
}

// Fused QKV: C[8192,3072] = xb @ Wcat^T + bcat, all bf16, global_load_lds staging.
// n<1024 -> Q (scaled by SCL*log2e) BHSD; n<2048 -> K BHSD; else -> V^T BHDS.
__global__ __launch_bounds__(256)
void gemm_qkv_kernel(const __bf16* __restrict__ A, const __bf16* __restrict__ W,
                     const float* __restrict__ bcat,
                     __bf16* __restrict__ Qb, __bf16* __restrict__ Kb,
                     __bf16* __restrict__ Vb)
{
  __shared__ __attribute__((aligned(16))) __bf16 As[128 * 32];
  __shared__ __attribute__((aligned(16))) __bf16 Ws[128 * 32];
  const int tid  = threadIdx.x;
  const int wave = tid >> 6, lane = tid & 63;
  const int l15  = lane & 15, quad = lane >> 4;
  const int wm   = wave >> 1, wn = wave & 1;
  const int bm   = blockIdx.y * 128;
  const int bn   = blockIdx.x * 128;        // 0..2944
  const int widx = bn >> 10;                // 0=Q 1=K 2=V (block-uniform)
  const float QS = 0.180336880f;            // (1/sqrt(64)) * log2(e)

  floatx4 acc[4][4];
#pragma unroll
  for (int i = 0; i < 4; ++i)
#pragma unroll
    for (int j = 0; j < 4; ++j) acc[i][j] = (floatx4){0.f, 0.f, 0.f, 0.f};

  const int srow = tid >> 2;          // 0..63
  const int scol = (tid & 3) << 3;    // 0,8,16,24
  const __bf16* Ag = A + (size_t)(bm + srow) * 1024 + scol;
  const __bf16* Wg = W + (size_t)(bn + srow) * 1024 + scol;
  __bf16* AsD = As + tid * 8;
  __bf16* WsD = Ws + tid * 8;

  for (int k0 = 0; k0 < 1024; k0 += 32) {
    __syncthreads();
    async_cp16(Ag + k0,             AsD);
    async_cp16(Ag + k0 + 64 * 1024, AsD + 2048);
    async_cp16(Wg + k0,             WsD);
    async_cp16(Wg + k0 + 64 * 1024, WsD + 2048);
    __syncthreads();
    short8 af[4], wf[4];
#pragma unroll
    for (int mi = 0; mi < 4; ++mi)
      af[mi] = *(const short8*)(As + ((wm * 64 + mi * 16 + l15) << 5) + (quad << 3));
#pragma unroll
    for (int ni = 0; ni < 4; ++ni)
      wf[ni] = *(const short8*)(Ws + ((wn * 64 + ni * 16 + l15) << 5) + (quad << 3));
#pragma unroll
    for (int mi = 0; mi < 4; ++mi)
#pragma unroll
      for (int ni = 0; ni < 4; ++ni)
        acc[mi][ni] = __builtin_amdgcn_mfma_f32_16x16x32_bf16(af[mi], wf[ni], acc[mi][ni], 0, 0, 0);
  }

#pragma unroll
  for (int ni = 0; ni < 4; ++ni) {
    const int n  = bn + wn * 64 + ni * 16 + l15;
    const float bvb = bcat[n];
    const int np = n & 1023;
    const int h = np >> 6, d = np & 63;
#pragma unroll
    for (int mi = 0; mi < 4; ++mi) {
      const int m0 = bm + wm * 64 + mi * 16 + quad * 4;
      const int b = m0 >> 11, s0 = m0 & 2047;
      floatx4 v = acc[mi][ni];
      if (widx == 0) {
        const size_t base = (size_t)(b * 16 + h) * (S_ * 64) + d;
#pragma unroll
        for (int r = 0; r < 4; ++r)
          Qb[base + (size_t)(s0 + r) * 64] = (__bf16)((v[r] + bvb) * QS);
      } else if (widx == 1) {
        const size_t base = (size_t)(b * 16 + h) * (S_ * 64) + d;
#pragma unroll
        for (int r = 0; r < 4; ++r)
          Kb[base + (size_t)(s0 + r) * 64] = (__bf16)(v[r] + bvb);
      } else {
        const size_t base = ((size_t)(b * 16 + h) * 64 + d) * S_ + s0;
        union { ushort4 u4; unsigned short u[4]; } pk;
#pragma unroll
        for (int r = 0; r < 4; ++r) {
          __bf16 hv = (__bf16)(v[r] + bvb);
          pk.u[r] = *(unsigned short*)&hv;
        }
        *(ushort4*)(Vb + base) = pk.u4;    // 8B aligned: s0 % 4 == 0
      }
    }
  }
}

// Flash attention, causal, exp2-domain (Q pre-scaled by SCL*log2e).
// Grid (bh=64, qtA=16): bh fastest -> XCD = bh%8; per-XCD K/V working set = L2.
// Block runs q-tiles {qtA, 31-qtA} sequentially (33 k-tile computes, balanced).
// K/V tiles staged via async global_load_lds (no VGPR round-trip, no prefetch
// registers held across barriers -> no spills). LDS layout is XOR-swizzled
// 16B chunks: chunk(r,c) at (r*8 + (c ^ (r&7)))*16B -- satisfies the
// wave-uniform+lane*16 constraint of global_load_lds AND gives conflict-free
// ds_read_b128 fragments (each bank hit exactly 8x/wave).
// l computed via MFMA with a constant all-ones B fragment (no LDS, no shuffle).
// Ps is per-wave private LDS (DS in-order within a wave) -> no barrier before PV.
// Output IN-PLACE over Q (block-owned rows).
__global__ __launch_bounds__(256, 4)
void attn_kernel(__bf16* __restrict__ Q, const __bf16* __restrict__ K,
                 const __bf16* __restrict__ Vt)
{
  __shared__ __attribute__((aligned(16))) __bf16 Ks[64 * 64];   // swizzled chunks
  __shared__ __attribute__((aligned(16))) __bf16 Vs[64 * 64];   // swizzled chunks
  __shared__ __attribute__((aligned(16))) __bf16 Ps[4][16 * 72];

  const int tid  = threadIdx.x;
  const int wave = tid >> 6, lane = tid & 63;
  const int l15  = lane & 15, quad = lane >> 4;
  const int bh   = blockIdx.x;             // fastest -> XCD = bh % 8
  const int qtA  = blockIdx.y;             // 0..15
  const size_t hb = (size_t)bh * (S_ * 64);
  const float MASKV = -1.0e30f;

  // constant all-ones B fragment (bf16 1.0 = 0x3F80) for the l accumulator
  const short ONE = (short)0x3F80;
  const short8 ones8 = {ONE, ONE, ONE, ONE, ONE, ONE, ONE, ONE};

  // staging geometry (per thread, loop-invariant)
  const int rho  = lane >> 3;              // 0..7
  const int cswz = ((lane & 7) ^ rho) * 8; // swizzled col offset (elems)
  // fragment-read swizzled col offsets (elems), per kk
  const int fsw0 = ((quad    ) ^ (l15 & 7)) * 8;   // kk=0: c = quad
  const int fsw1 = ((quad + 4) ^ (l15 & 7)) * 8;   // kk=1: c = quad+4

  for (int qsel = 0; qsel < 2; ++qsel) {
    const int qt = qsel ? (31 - qtA) : qtA;
    const int qw = qt * 64 + wave * 16;     // wave's first q row

    // Q fragments in registers: A[m=l15][k=kk*32+quad*8+j]
    short8 aq[2];
#pragma unroll
    for (int kk = 0; kk < 2; ++kk)
      aq[kk] = *(const short8*)(Q + hb + (size_t)(qw + l15) * 64 + kk * 32 + quad * 8);

    floatx4 oacc[4];
#pragma unroll
    for (int j = 0; j < 4; ++j) oacc[j] = (floatx4){0.f, 0.f, 0.f, 0.f};
    floatx4 lacc = (floatx4){0.f, 0.f, 0.f, 0.f};
    float mst[4];
#pragma unroll
    for (int r = 0; r < 4; ++r) mst[r] = MASKV;

    for (int kt = 0; kt <= qt; ++kt) {
      __syncthreads();                // prev tile's LDS reads done
      // async stage K tile [64x64] and V^T tile [64x64], swizzled chunks.
      // wave w, iter t covers rows (t*4+w)*8 + rho; 128B-contiguous per rho.
#pragma unroll
      for (int t = 0; t < 2; ++t) {
        const int rb = (t * 4 + wave) * 8 + rho;
        const int ci = ((t * 4 + wave) * 64 + lane) * 8;   // LDS elem index
        async_cp16(K  + hb + (size_t)(kt * 64 + rb) * 64 + cswz, &Ks[ci]);
        async_cp16(Vt + hb + (size_t)rb * S_ + kt * 64 + cswz,   &Vs[ci]);
      }
      __syncthreads();                // drains vmcnt -> staged tile visible

      // S = Q K^T (pre-scaled by SCL*log2e)
      floatx4 sacc[4];
#pragma unroll
      for (int j = 0; j < 4; ++j) sacc[j] = (floatx4){0.f, 0.f, 0.f, 0.f};
#pragma unroll
      for (int kk = 0; kk < 2; ++kk) {
        const int fsw = kk ? fsw1 : fsw0;
        short8 bk[4];
#pragma unroll
        for (int ni = 0; ni < 4; ++ni)
          bk[ni] = *(const short8*)(&Ks[(ni * 16 + l15) * 64 + fsw]);
#pragma unroll
        for (int ni = 0; ni < 4; ++ni)
          sacc[ni] = __builtin_amdgcn_mfma_f32_16x16x32_bf16(aq[kk], bk[ni], sacc[ni], 0, 0, 0);
      }

      // online softmax (exp2 domain). Mask only on the diagonal tile.
      const bool needmask = (kt == qt);
      const int sc0 = kt * 64 + l15;
#pragma unroll
      for (int r = 0; r < 4; ++r) {
        const int qg = qw + quad * 4 + r;
        float z[4];
        if (needmask) {
#pragma unroll
          for (int ni = 0; ni < 4; ++ni) {
            float zz = sacc[ni][r];
            if (sc0 + ni * 16 > qg) zz = MASKV;   // causal: key > query
            z[ni] = zz;
          }
        } else {
#pragma unroll
          for (int ni = 0; ni < 4; ++ni) z[ni] = sacc[ni][r];
        }
        float tmax = fmaxf(fmaxf(z[0], z[1]), fmaxf(z[2], z[3]));
        tmax = fmaxf(tmax, __shfl_xor(tmax, 1));
        tmax = fmaxf(tmax, __shfl_xor(tmax, 2));
        tmax = fmaxf(tmax, __shfl_xor(tmax, 4));
        tmax = fmaxf(tmax, __shfl_xor(tmax, 8));
        const float mold = mst[r];
        const float mnew = fmaxf(mold, tmax);
        mst[r] = mnew;
        const float alpha = EXP2F(mold - mnew);
#pragma unroll
        for (int ni = 0; ni < 4; ++ni) {
          const float p = EXP2F(z[ni] - mnew);
          Ps[wave][(quad * 4 + r) * 72 + ni * 16 + l15] = (__bf16)p;
        }
#pragma unroll
        for (int ni = 0; ni < 4; ++ni) oacc[ni][r] *= alpha;
        lacc[r] *= alpha;
      }

      // per-wave Ps round-trip: DS ops of one wave are in-order; no barrier.
      // O += P(16x64) @ V(64x64); l += P @ ones (constant fragment)
#pragma unroll
      for (int kk = 0; kk < 2; ++kk) {
        const int fsw = kk ? fsw1 : fsw0;
        const short8 ap = *(const short8*)(&Ps[wave][l15 * 72 + kk * 32 + quad * 8]);
        short8 bv[4];
#pragma unroll
        for (int ni = 0; ni < 4; ++ni)
          bv[ni] = *(const short8*)(&Vs[(ni * 16 + l15) * 64 + fsw]);
#pragma unroll
        for (int ni = 0; ni < 4; ++ni)
          oacc[ni] = __builtin_amdgcn_mfma_f32_16x16x32_bf16(ap, bv[ni], oacc[ni], 0, 0, 0);
        lacc = __builtin_amdgcn_mfma_f32_16x16x32_bf16(ap, ones8, lacc, 0, 0, 0);
      }
    }

    // epilogue: every lane's lacc[r] already holds l for row quad*4+r
#pragma unroll
    for (int r = 0; r < 4; ++r) {
      const float inv = 1.0f / fmaxf(lacc[r], 1e-20f);
      const int qg = qw + quad * 4 + r;
      const size_t rowb = hb + (size_t)qg * 64;
#pragma unroll
      for (int ni = 0; ni < 4; ++ni)
        Q[rowb + ni * 16 + l15] = (__bf16)(oacc[ni][r] * inv);
    }
  }
}

// Final projection: A = attn output (bf16, BHSD gather), W = Wob bf16,
// bias fp32, out fp32 row-major. global_load_lds staging.
__global__ __launch_bounds__(256)
void gemm_o_kernel(const __bf16* __restrict__ A, const __bf16* __restrict__ W,
                   const float* __restrict__ bias, float* __restrict__ out)
{
  __shared__ __attribute__((aligned(16))) __bf16 As[128 * 32];
  __shared__ __attribute__((aligned(16))) __bf16 Ws[128 * 32];
  const int tid  = threadIdx.x;
  const int wave = tid >> 6, lane = tid & 63;
  const int l15  = lane & 15, quad = lane >> 4;
  const int wm   = wave >> 1, wn = wave & 1;
  const int bm   = blockIdx.y * 128;
  const int bn   = blockIdx.x * 128;

  floatx4 acc[4][4];
#pragma unroll
  for (int i = 0; i < 4; ++i)
#pragma unroll
    for (int j = 0; j < 4; ++j) acc[i][j] = (floatx4){0.f, 0.f, 0.f, 0.f};

  const int srow = tid >> 2;
  const int scol = (tid & 3) << 3;
  const __bf16* Wg = W + (size_t)(bn + srow) * 1024 + scol;
  const int bb = bm >> 11;                 // batch
  const int ss = (bm & 2047) + srow;       // seq
  __bf16* AsD = As + tid * 8;
  __bf16* WsD = Ws + tid * 8;

  for (int k0 = 0; k0 < 1024; k0 += 32) {
    const int c = k0 + scol, h = c >> 6, dd = c & 63;  // 8 elems never cross a head
    const __bf16* pa0 = A + (((size_t)(bb * 16 + h) * S_) + ss) * 64 + dd;
    __syncthreads();
    async_cp16(pa0,           AsD);
    async_cp16(pa0 + 64 * 64, AsD + 2048);             // s -> s+64
    async_cp16(Wg + k0,             WsD);
    async_cp16(Wg + k0 + 64 * 1024, WsD + 2048);
    __syncthreads();

    short8 af[4], wf[4];
#pragma unroll
    for (int mi = 0; mi < 4; ++mi)
      af[mi] = *(const short8*)(As + ((wm * 64 + mi * 16 + l15) << 5) + (quad << 3));
#pragma unroll
    for (int ni = 0; ni < 4; ++ni)
      wf[ni] = *(const short8*)(Ws + ((wn * 64 + ni * 16 + l15) << 5) + (quad << 3));
#pragma unroll
    for (int mi = 0; mi < 4; ++mi)
#pragma unroll
      for (int ni = 0; ni < 4; ++ni)
        acc[mi][ni] = __builtin_amdgcn_mfma_f32_16x16x32_bf16(af[mi], wf[ni], acc[mi][ni], 0, 0, 0);
  }

#pragma unroll
  for (int ni = 0; ni < 4; ++ni) {
    const int n = bn + wn * 64 + ni * 16 + l15;
    const float bvb = bias[n];
#pragma unroll
    for (int mi = 0; mi < 4; ++mi) {
      const int m0 = bm + wm * 64 + mi * 16 + quad * 4;
      floatx4 v = acc[mi][ni];
#pragma unroll
      for (int r = 0; r < 4; ++r)
        out[(size_t)(m0 + r) * 1024 + n] = v[r] + bvb;
    }
  }
}

extern "C" void kernel_launch(void* const* d_in, const int* in_sizes, int n_in,
                              void* d_out, int out_size, void* d_ws, size_t ws_size,
                              hipStream_t stream) {
  const float* x  = (const float*)d_in[0];
  const float* Wq = (const float*)d_in[1];
  const float* bq = (const float*)d_in[2];
  const float* Wk = (const float*)d_in[3];
  const float* bk = (const float*)d_in[4];
  const float* Wv = (const float*)d_in[5];
  const float* bv = (const float*)d_in[6];
  const float* Wo = (const float*)d_in[7];
  const float* bo = (const float*)d_in[8];
  // d_in[9] = causal_mask (int32) — causality implemented analytically, unused.

  const size_t BUF = (size_t)B_ * NH_ * S_ * HD_;   // 8388608 elems
  __bf16* ws   = (__bf16*)d_ws;                     // ws usage: ~42 MB
  __bf16* xb   = ws;                                // 8388608  (16.8 MB)
  __bf16* Wcat = ws + 8388608;                      // 3145728  (6 MB)
  __bf16* Wob  = ws + 11534336;                     // 1048576  (2 MB)
  __bf16* Qb   = ws + 12582912;                     // 8388608  (16.8 MB)
  float*  bcat = (float*)(ws + 20971520);           // 3072 fp32 (12 KB)
  __bf16* Kb   = (__bf16*)d_out;                    // d_out reused as K+V^T
  __bf16* Vb   = (__bf16*)d_out + BUF;              // scratch until attn done

  dim3 blk(256);
  cvt_kernel<<<12291, blk, 0, stream>>>(x, Wq, Wk, Wv, Wo, bq, bk, bv,
                                        xb, Wcat, Wob, bcat);
  gemm_qkv_kernel<<<dim3(24, 64), blk, 0, stream>>>(xb, Wcat, bcat, Qb, Kb, Vb);
  attn_kernel<<<dim3(64, 16), blk, 0, stream>>>(Qb, Kb, Vb);
  gemm_o_kernel<<<dim3(8, 64), blk, 0, stream>>>(Qb, Wob, bo, (float*)d_out);
}